// Round 11
// baseline (1288.483 us; speedup 1.0000x reference)
//
#include <hip/hip_runtime.h>

#define Bq 8
#define Nq 8192
#define NPOINT 1024
#define NSAMPLE 32
#define DF 64
#define CH 67                      /* 3 + DF */
#define RAD2 0.0625f
#define FPS_T 1024
#define FPS_PPT (Nq / FPS_T)       /* 8 */
#define FPS_PAIRS (FPS_PPT / 2)    /* 4 */
#define QCHUNK 16                  /* queries per chunk = waves per block */
#define CHUNKS_PER_B (NPOINT / QCHUNK)   /* 64 */
#define NCHUNK (Bq * CHUNKS_PER_B)       /* 512 */
#define PUB_EVERY 64
#define NBLK 256

typedef float v2f __attribute__((ext_vector_type(2)));

// One u64-max DPP step: combine with lane given by dpp_ctrl (VALU pipe).
#define DPP_STEP_U64(k, CTRL)                                                 \
    {                                                                         \
        unsigned int lo = (unsigned int)k, hi = (unsigned int)(k >> 32);      \
        unsigned int nlo = (unsigned int)__builtin_amdgcn_update_dpp(         \
            (int)lo, (int)lo, CTRL, 0xf, 0xf, false);                         \
        unsigned int nhi = (unsigned int)__builtin_amdgcn_update_dpp(         \
            (int)hi, (int)hi, CTRL, 0xf, 0xf, false);                         \
        unsigned long long nk = ((unsigned long long)nhi << 32) | nlo;        \
        if (nk > k) k = nk;                                                   \
    }

// 16-lane-row butterfly max: xor1, xor2, half_mirror, mirror.
__device__ __forceinline__ unsigned long long rowmax16(unsigned long long k)
{
    DPP_STEP_U64(k, 0xB1) DPP_STEP_U64(k, 0x4E)
    DPP_STEP_U64(k, 0x141) DPP_STEP_U64(k, 0x140)
    return k;
}

__device__ __forceinline__ unsigned long long readlane_u64(unsigned long long k, int l)
{
    const unsigned int lo = (unsigned int)__builtin_amdgcn_readlane((int)(unsigned int)k, l);
    const unsigned int hi = (unsigned int)__builtin_amdgcn_readlane((int)(unsigned int)(k >> 32), l);
    return ((unsigned long long)hi << 32) | lo;
}

// ---------------------------------------------------------------------------
// Fused producer-consumer kernel, 256 blocks x 1024 threads (1 block/CU).
// Blocks 0..7: round-8 FPS (verbatim arithmetic), publishing prog[b] every
// PUB_EVERY iters with a device-scope release store. All blocks then loop:
// grab a 16-query chunk via atomicAdd(ctr), acquire-poll prog[batch], each
// wave = one query: ballq scan (verbatim) + fused fill of its 32x67 slice.
// Deadlock-free: producers never wait on consumers; bounded-spin failsafe.
// ---------------------------------------------------------------------------
__global__ void __launch_bounds__(FPS_T, 1)
fused_kernel(const float* __restrict__ xyz, const float* __restrict__ points,
             float* __restrict__ out, int* __restrict__ ws)
{
#pragma clang fp contract(off)
    extern __shared__ float lds[];
    float4* tab = (float4*)lds;                     // 8192 * 16B = 128 KB
    __shared__ unsigned long long wbest[2][64];     // [parity][wave*4+row]
    __shared__ int s_cid;

    int* ctr  = ws;                                 // zeroed by memsetAsync
    int* prog = ws + 4;                             // prog[8]
    float* new_xyz    = out;                        // Bq*NPOINT*3
    float* new_points = out + Bq * NPOINT * 3;

    const int blk  = blockIdx.x;
    const int t    = threadIdx.x;
    const int lane = t & 63;
    const int wid  = t >> 6;

    // ---------------- producer phase (blocks 0..7) ----------------
    if (blk < Bq) {
        const int b = blk;
        const float* xb = xyz + (size_t)b * Nq * 3;

        v2f px[FPS_PAIRS], py[FPS_PAIRS], pz[FPS_PAIRS], dist[FPS_PAIRS];
        int i0c[FPS_PAIRS], i1c[FPS_PAIRS];
#pragma unroll
        for (int k = 0; k < FPS_PAIRS; ++k) {
            const int i0 = t + (2 * k + 0) * FPS_T;
            const int i1 = t + (2 * k + 1) * FPS_T;
            i0c[k] = i0; i1c[k] = i1;
            const float x0 = xb[i0 * 3 + 0], y0 = xb[i0 * 3 + 1], z0 = xb[i0 * 3 + 2];
            const float x1 = xb[i1 * 3 + 0], y1 = xb[i1 * 3 + 1], z1 = xb[i1 * 3 + 2];
            px[k] = (v2f){x0, x1}; py[k] = (v2f){y0, y1}; pz[k] = (v2f){z0, z1};
            dist[k] = (v2f){1e10f, 1e10f};
            tab[i0] = make_float4(x0, y0, z0, 0.0f);
            tab[i1] = make_float4(x1, y1, z1, 0.0f);
        }
        __syncthreads();

        float4 c = tab[0];                          // centroid 0 = point 0
        float* ob = new_xyz + (size_t)b * NPOINT * 3;

        for (int it = 0; it < NPOINT; ++it) {
            if (t == 0) {
                ob[it * 3 + 0] = c.x;
                ob[it * 3 + 1] = c.y;
                ob[it * 3 + 2] = c.z;
                if ((it & (PUB_EVERY - 1)) == (PUB_EVERY - 1))
                    __hip_atomic_store(prog + b, it + 1, __ATOMIC_RELEASE,
                                       __HIP_MEMORY_SCOPE_AGENT);
            }
            const v2f cx2 = (v2f){c.x, c.x};
            const v2f cy2 = (v2f){c.y, c.y};
            const v2f cz2 = (v2f){c.z, c.z};
            float bv = -1.0f;
            int   bi = Nq;
#pragma unroll
            for (int k = 0; k < FPS_PAIRS; ++k) {
                const v2f dx = px[k] - cx2;         // v_pk_add (neg)
                const v2f dy = py[k] - cy2;
                const v2f dz = pz[k] - cz2;
                const v2f sx = dx * dx;             // v_pk_mul
                const v2f sy = dy * dy;
                const v2f sz = dz * dz;
                const v2f d  = (sx + sy) + sz;      // v_pk_add, L-to-R chain
                const v2f nd = __builtin_elementwise_min(dist[k], d);
                dist[k] = nd;
                if (nd.x > bv) { bv = nd.x; bi = i0c[k]; }  // strict >, asc idx
                if (nd.y > bv) { bv = nd.y; bi = i1c[k]; }
            }
            unsigned long long k64 =
                ((unsigned long long)__float_as_uint(bv) << 32) |
                (unsigned int)(~bi);
            k64 = rowmax16(k64);
            if ((lane & 15) == 0) wbest[it & 1][wid * 4 + (lane >> 4)] = k64;
            __syncthreads();
            unsigned long long g = wbest[it & 1][lane];
            g = rowmax16(g);
            DPP_STEP_U64(g, 0x142)                  // row_bcast15
            DPP_STEP_U64(g, 0x143)                  // row_bcast31
            g = readlane_u64(g, 63);
            const int far = (int)(~(unsigned int)(g & 0xffffffffull));
            c = tab[far];                           // uniform addr broadcast
        }
        __syncthreads();                            // tab dead after this
    }

    // ---------------- consumer phase (all blocks) ----------------
    int* selbase = (int*)lds;                       // reuse dynamic LDS
    for (;;) {
        if (t == 0) s_cid = atomicAdd(ctr, 1);
        __syncthreads();
        const int cid = s_cid;
        if (cid >= NCHUNK) break;
        const int cb = cid >> 6;                    // batch
        const int q0 = (cid & (CHUNKS_PER_B - 1)) * QCHUNK;
        if (t == 0) {
            const int need = q0 + QCHUNK;
            int spins = 0;
            while (__hip_atomic_load(prog + cb, __ATOMIC_ACQUIRE,
                                     __HIP_MEMORY_SCOPE_AGENT) < need) {
                __builtin_amdgcn_s_sleep(32);
                if (++spins > (1 << 20)) break;     // failsafe: fail visibly
            }
        }
        __syncthreads();

        // wave wid handles query q0+wid of batch cb
        const int gq = cb * NPOINT + q0 + wid;
        int* selw = selbase + wid * NSAMPLE;
        const float* xb = xyz + (size_t)cb * Nq * 3;
        const float qx = new_xyz[gq * 3 + 0];
        const float qy = new_xyz[gq * 3 + 1];
        const float qz = new_xyz[gq * 3 + 2];
        const float ssrc = qx * qx + qy * qy + qz * qz;   // plain chain
        int cnt = 0;
        for (int base = 0; base < Nq; base += 64) {
            const int i = base + lane;
            const float px_ = xb[i * 3 + 0];
            const float py_ = xb[i * 3 + 1];
            const float pz_ = xb[i * 3 + 2];
            const float dot  = __builtin_fmaf(pz_, qz, __builtin_fmaf(py_, qy, px_ * qx));
            const float sdst = px_ * px_ + py_ * py_ + pz_ * pz_;  // plain chain
            const float d    = (-2.0f * dot + ssrc) + sdst;
            const bool  in   = (d <= RAD2);
            const unsigned long long m = __ballot(in);
            if (in) {
                const int slot = cnt + (int)__popcll(m & ((1ull << lane) - 1ull));
                if (slot < NSAMPLE) selw[slot] = i;
            }
            cnt += (int)__popcll(m);
            if (cnt >= NSAMPLE) break;
        }
        const int first = selw[0];
        if (cnt < NSAMPLE) {
            for (int s = cnt + lane; s < NSAMPLE; s += 64) selw[s] = first;
        }
        // fused fill: 32 samples x 67 channels, contiguous per query
        const float* pb = points + (size_t)cb * Nq * DF;
        float* op = new_points + (size_t)gq * (NSAMPLE * CH);
        for (int e = lane; e < NSAMPLE * CH; e += 64) {
            const int s  = e / CH;
            const int cc = e - s * CH;
            const int idx = selw[s];
            float v;
            if (cc < 3) v = xb[idx * 3 + cc] - new_xyz[gq * 3 + cc];
            else        v = pb[(size_t)idx * DF + (cc - 3)];
            op[e] = v;
        }
        __syncthreads();                            // protect s_cid / selw
    }
}

// ---------------------------------------------------------------------------
extern "C" void kernel_launch(void* const* d_in, const int* in_sizes, int n_in,
                              void* d_out, int out_size, void* d_ws, size_t ws_size,
                              hipStream_t stream)
{
    (void)in_sizes; (void)n_in; (void)out_size; (void)ws_size;
    const float* xyz    = (const float*)d_in[0];
    const float* points = (const float*)d_in[1];
    float* out = (float*)d_out;
    int*   ws  = (int*)d_ws;

    hipFuncSetAttribute(reinterpret_cast<const void*>(fused_kernel),
                        hipFuncAttributeMaxDynamicSharedMemorySize,
                        Nq * (int)sizeof(float4));

    hipMemsetAsync(d_ws, 0, 64, stream);            // ctr + prog[8]
    fused_kernel<<<NBLK, FPS_T, Nq * sizeof(float4), stream>>>(xyz, points, out, ws);
}

// Round 12
// 1283.602 us; speedup vs baseline: 1.0038x; 1.0038x over previous
//
#include <hip/hip_runtime.h>

#define Bq 8
#define Nq 8192
#define NPOINT 1024
#define NSAMPLE 32
#define DF 64
#define CH 67                      /* 3 + DF */
#define RAD2 0.0625f
#define FPS_T 1024
#define FPS_PPT (Nq / FPS_T)       /* 8 */
#define FPS_PAIRS (FPS_PPT / 2)    /* 4 */
#define QCHUNK 16                  /* queries per chunk = waves per block */
#define CHUNKS_PER_B (NPOINT / QCHUNK)   /* 64 */
#define NCHUNK (Bq * CHUNKS_PER_B)       /* 512 */
#define PUB_EVERY 256
#define NBLK 256

typedef float v2f __attribute__((ext_vector_type(2)));

// One u64-max DPP step: combine with lane given by dpp_ctrl (VALU pipe).
#define DPP_STEP_U64(k, CTRL)                                                 \
    {                                                                         \
        unsigned int lo = (unsigned int)k, hi = (unsigned int)(k >> 32);      \
        unsigned int nlo = (unsigned int)__builtin_amdgcn_update_dpp(         \
            (int)lo, (int)lo, CTRL, 0xf, 0xf, false);                         \
        unsigned int nhi = (unsigned int)__builtin_amdgcn_update_dpp(         \
            (int)hi, (int)hi, CTRL, 0xf, 0xf, false);                         \
        unsigned long long nk = ((unsigned long long)nhi << 32) | nlo;        \
        if (nk > k) k = nk;                                                   \
    }

// 16-lane-row butterfly max: xor1, xor2, half_mirror, mirror.
__device__ __forceinline__ unsigned long long rowmax16(unsigned long long k)
{
    DPP_STEP_U64(k, 0xB1) DPP_STEP_U64(k, 0x4E)
    DPP_STEP_U64(k, 0x141) DPP_STEP_U64(k, 0x140)
    return k;
}

__device__ __forceinline__ unsigned long long readlane_u64(unsigned long long k, int l)
{
    const unsigned int lo = (unsigned int)__builtin_amdgcn_readlane((int)(unsigned int)k, l);
    const unsigned int hi = (unsigned int)__builtin_amdgcn_readlane((int)(unsigned int)(k >> 32), l);
    return ((unsigned long long)hi << 32) | lo;
}

// ---------------------------------------------------------------------------
// Fused producer-consumer kernel, 256 blocks x 1024 threads (1 block/CU).
// Blocks 0..7: round-8 FPS (verbatim arithmetic), publishing prog[b] every
// PUB_EVERY iters with a device-scope release store (writeback volume kept
// tiny by nt consumer stores). All blocks then loop: grab a 16-query chunk
// via atomicAdd(ctr), acquire-poll prog[batch], each wave = one query:
// ballq scan (verbatim) + fused fill (nt stores) of its 32x67 slice.
// Deadlock-free: producers never wait on consumers; bounded-spin failsafe.
// ---------------------------------------------------------------------------
__global__ void __launch_bounds__(FPS_T, 1)
fused_kernel(const float* __restrict__ xyz, const float* __restrict__ points,
             float* __restrict__ out, int* __restrict__ ws)
{
#pragma clang fp contract(off)
    extern __shared__ float lds[];
    float4* tab = (float4*)lds;                     // 8192 * 16B = 128 KB
    __shared__ unsigned long long wbest[2][64];     // [parity][wave*4+row]
    __shared__ int s_cid;

    int* ctr  = ws;                                 // zeroed by memsetAsync
    int* prog = ws + 4;                             // prog[8]
    float* new_xyz    = out;                        // Bq*NPOINT*3
    float* new_points = out + Bq * NPOINT * 3;

    const int blk  = blockIdx.x;
    const int t    = threadIdx.x;
    const int lane = t & 63;
    const int wid  = t >> 6;

    // ---------------- producer phase (blocks 0..7) ----------------
    if (blk < Bq) {
        const int b = blk;
        const float* xb = xyz + (size_t)b * Nq * 3;

        v2f px[FPS_PAIRS], py[FPS_PAIRS], pz[FPS_PAIRS], dist[FPS_PAIRS];
        int i0c[FPS_PAIRS], i1c[FPS_PAIRS];
#pragma unroll
        for (int k = 0; k < FPS_PAIRS; ++k) {
            const int i0 = t + (2 * k + 0) * FPS_T;
            const int i1 = t + (2 * k + 1) * FPS_T;
            i0c[k] = i0; i1c[k] = i1;
            const float x0 = xb[i0 * 3 + 0], y0 = xb[i0 * 3 + 1], z0 = xb[i0 * 3 + 2];
            const float x1 = xb[i1 * 3 + 0], y1 = xb[i1 * 3 + 1], z1 = xb[i1 * 3 + 2];
            px[k] = (v2f){x0, x1}; py[k] = (v2f){y0, y1}; pz[k] = (v2f){z0, z1};
            dist[k] = (v2f){1e10f, 1e10f};
            tab[i0] = make_float4(x0, y0, z0, 0.0f);
            tab[i1] = make_float4(x1, y1, z1, 0.0f);
        }
        __syncthreads();

        float4 c = tab[0];                          // centroid 0 = point 0
        float* ob = new_xyz + (size_t)b * NPOINT * 3;

        for (int it = 0; it < NPOINT; ++it) {
            if (t == 0) {
                ob[it * 3 + 0] = c.x;
                ob[it * 3 + 1] = c.y;
                ob[it * 3 + 2] = c.z;
                if ((it & (PUB_EVERY - 1)) == (PUB_EVERY - 1))
                    __hip_atomic_store(prog + b, it + 1, __ATOMIC_RELEASE,
                                       __HIP_MEMORY_SCOPE_AGENT);
            }
            const v2f cx2 = (v2f){c.x, c.x};
            const v2f cy2 = (v2f){c.y, c.y};
            const v2f cz2 = (v2f){c.z, c.z};
            float bv = -1.0f;
            int   bi = Nq;
#pragma unroll
            for (int k = 0; k < FPS_PAIRS; ++k) {
                const v2f dx = px[k] - cx2;         // v_pk_add (neg)
                const v2f dy = py[k] - cy2;
                const v2f dz = pz[k] - cz2;
                const v2f sx = dx * dx;             // v_pk_mul
                const v2f sy = dy * dy;
                const v2f sz = dz * dz;
                const v2f d  = (sx + sy) + sz;      // v_pk_add, L-to-R chain
                const v2f nd = __builtin_elementwise_min(dist[k], d);
                dist[k] = nd;
                if (nd.x > bv) { bv = nd.x; bi = i0c[k]; }  // strict >, asc idx
                if (nd.y > bv) { bv = nd.y; bi = i1c[k]; }
            }
            unsigned long long k64 =
                ((unsigned long long)__float_as_uint(bv) << 32) |
                (unsigned int)(~bi);
            k64 = rowmax16(k64);
            if ((lane & 15) == 0) wbest[it & 1][wid * 4 + (lane >> 4)] = k64;
            __syncthreads();
            unsigned long long g = wbest[it & 1][lane];
            g = rowmax16(g);
            DPP_STEP_U64(g, 0x142)                  // row_bcast15
            DPP_STEP_U64(g, 0x143)                  // row_bcast31
            g = readlane_u64(g, 63);
            const int far = (int)(~(unsigned int)(g & 0xffffffffull));
            c = tab[far];                           // uniform addr broadcast
        }
        __syncthreads();                            // tab dead after this
    }

    // ---------------- consumer phase (all blocks) ----------------
    int* selbase = (int*)lds;                       // reuse dynamic LDS
    for (;;) {
        if (t == 0) s_cid = atomicAdd(ctr, 1);
        __syncthreads();
        const int cid = s_cid;
        if (cid >= NCHUNK) break;
        const int cb = cid >> 6;                    // batch
        const int q0 = (cid & (CHUNKS_PER_B - 1)) * QCHUNK;
        if (t == 0) {
            const int need = q0 + QCHUNK;
            int spins = 0;
            while (__hip_atomic_load(prog + cb, __ATOMIC_ACQUIRE,
                                     __HIP_MEMORY_SCOPE_AGENT) < need) {
                __builtin_amdgcn_s_sleep(32);
                if (++spins > (1 << 20)) break;     // failsafe: fail visibly
            }
        }
        __syncthreads();

        // wave wid handles query q0+wid of batch cb
        const int gq = cb * NPOINT + q0 + wid;
        int* selw = selbase + wid * NSAMPLE;
        const float* xb = xyz + (size_t)cb * Nq * 3;
        const float qx = new_xyz[gq * 3 + 0];
        const float qy = new_xyz[gq * 3 + 1];
        const float qz = new_xyz[gq * 3 + 2];
        const float ssrc = qx * qx + qy * qy + qz * qz;   // plain chain
        int cnt = 0;
        for (int base = 0; base < Nq; base += 64) {
            const int i = base + lane;
            const float px_ = xb[i * 3 + 0];
            const float py_ = xb[i * 3 + 1];
            const float pz_ = xb[i * 3 + 2];
            const float dot  = __builtin_fmaf(pz_, qz, __builtin_fmaf(py_, qy, px_ * qx));
            const float sdst = px_ * px_ + py_ * py_ + pz_ * pz_;  // plain chain
            const float d    = (-2.0f * dot + ssrc) + sdst;
            const bool  in   = (d <= RAD2);
            const unsigned long long m = __ballot(in);
            if (in) {
                const int slot = cnt + (int)__popcll(m & ((1ull << lane) - 1ull));
                if (slot < NSAMPLE) selw[slot] = i;
            }
            cnt += (int)__popcll(m);
            if (cnt >= NSAMPLE) break;
        }
        const int first = selw[0];
        if (cnt < NSAMPLE) {
            for (int s = cnt + lane; s < NSAMPLE; s += 64) selw[s] = first;
        }
        // fused fill: 32 samples x 67 channels, nt stores (write-once data;
        // keeps L2 clean so the producer's release-writeback stays cheap)
        const float* pb = points + (size_t)cb * Nq * DF;
        float* op = new_points + (size_t)gq * (NSAMPLE * CH);
        for (int e = lane; e < NSAMPLE * CH; e += 64) {
            const int s  = e / CH;
            const int cc = e - s * CH;
            const int idx = selw[s];
            float v;
            if (cc < 3) v = xb[idx * 3 + cc] - new_xyz[gq * 3 + cc];
            else        v = pb[(size_t)idx * DF + (cc - 3)];
            __builtin_nontemporal_store(v, op + e);
        }
        __syncthreads();                            // protect s_cid / selw
    }
}

// ---------------------------------------------------------------------------
extern "C" void kernel_launch(void* const* d_in, const int* in_sizes, int n_in,
                              void* d_out, int out_size, void* d_ws, size_t ws_size,
                              hipStream_t stream)
{
    (void)in_sizes; (void)n_in; (void)out_size; (void)ws_size;
    const float* xyz    = (const float*)d_in[0];
    const float* points = (const float*)d_in[1];
    float* out = (float*)d_out;
    int*   ws  = (int*)d_ws;

    hipFuncSetAttribute(reinterpret_cast<const void*>(fused_kernel),
                        hipFuncAttributeMaxDynamicSharedMemorySize,
                        Nq * (int)sizeof(float4));

    hipMemsetAsync(d_ws, 0, 64, stream);            // ctr + prog[8]
    fused_kernel<<<NBLK, FPS_T, Nq * sizeof(float4), stream>>>(xyz, points, out, ws);
}

// Round 13
// 1280.034 us; speedup vs baseline: 1.0066x; 1.0028x over previous
//
#include <hip/hip_runtime.h>

#define Bq 8
#define Nq 8192
#define NPOINT 1024
#define NSAMPLE 32
#define DF 64
#define RAD2 0.0625f
#define FPS_T 1024
#define FPS_PPT (Nq / FPS_T) /* 8 */
#define FPS_PAIRS (FPS_PPT / 2)

typedef float v2f __attribute__((ext_vector_type(2)));

// One u64-max DPP step: combine with lane given by dpp_ctrl (VALU pipe).
#define DPP_STEP_U64(k, CTRL)                                                 \
    {                                                                         \
        unsigned int lo = (unsigned int)k, hi = (unsigned int)(k >> 32);      \
        unsigned int nlo = (unsigned int)__builtin_amdgcn_update_dpp(         \
            (int)lo, (int)lo, CTRL, 0xf, 0xf, false);                         \
        unsigned int nhi = (unsigned int)__builtin_amdgcn_update_dpp(         \
            (int)hi, (int)hi, CTRL, 0xf, 0xf, false);                         \
        unsigned long long nk = ((unsigned long long)nhi << 32) | nlo;        \
        if (nk > k) k = nk;                                                   \
    }

// 16-lane-row butterfly max: xor1 (0xB1), xor2 (0x4E), half_mirror (0x141),
// mirror (0x140). Every lane ends with its row's max.
__device__ __forceinline__ unsigned long long rowmax16(unsigned long long k)
{
    DPP_STEP_U64(k, 0xB1) DPP_STEP_U64(k, 0x4E)
    DPP_STEP_U64(k, 0x141) DPP_STEP_U64(k, 0x140)
    return k;
}

__device__ __forceinline__ unsigned long long readlane_u64(unsigned long long k, int l)
{
    const unsigned int lo = (unsigned int)__builtin_amdgcn_readlane((int)(unsigned int)k, l);
    const unsigned int hi = (unsigned int)__builtin_amdgcn_readlane((int)(unsigned int)(k >> 32), l);
    return ((unsigned long long)hi << 32) | lo;
}

// ---------------------------------------------------------------------------
// Kernel 1: FPS, one block (1024 thr, 16 waves) per batch.
// Points in REGISTERS (packed v2f pairs -> v_pk_*_f32), no LDS in hot loop.
// One barrier/iter. Reduce: rowmax16 -> 4 row leaders/wave write (64 LDS
// entries) -> every wave reads wbest[lane], rowmax16 + row_bcast15/31
// collapse -> readlane(63). All cross-lane traffic on the VALU DPP pipe.
// Bit-exact: d = ((dx*dx)+(dy*dy))+(dz*dz) plain chain (contract off), fminf,
// first-occurrence argmax: strict > over ascending per-thread indices, then
// commutative max over packed u64 (d_bits<<32 | ~i) == (max d, tie min i).
// ---------------------------------------------------------------------------
__global__ void __launch_bounds__(FPS_T, 1)
fps_kernel(const float* __restrict__ xyz, float* __restrict__ new_xyz)
{
#pragma clang fp contract(off)
    extern __shared__ float lds[];
    float4* tab = (float4*)lds;                     // 8192 * 16B = 128 KB
    __shared__ unsigned long long wbest[2][64];     // [parity][wave*4+row]

    const int b    = blockIdx.x;
    const int t    = threadIdx.x;
    const int lane = t & 63;
    const int wid  = t >> 6;
    const float* xb = xyz + (size_t)b * Nq * 3;

    v2f px[FPS_PAIRS], py[FPS_PAIRS], pz[FPS_PAIRS], dist[FPS_PAIRS];
    int i0c[FPS_PAIRS], i1c[FPS_PAIRS];             // hoisted index constants
#pragma unroll
    for (int k = 0; k < FPS_PAIRS; ++k) {
        const int i0 = t + (2 * k + 0) * FPS_T;
        const int i1 = t + (2 * k + 1) * FPS_T;
        i0c[k] = i0; i1c[k] = i1;
        const float x0 = xb[i0 * 3 + 0], y0 = xb[i0 * 3 + 1], z0 = xb[i0 * 3 + 2];
        const float x1 = xb[i1 * 3 + 0], y1 = xb[i1 * 3 + 1], z1 = xb[i1 * 3 + 2];
        px[k] = (v2f){x0, x1}; py[k] = (v2f){y0, y1}; pz[k] = (v2f){z0, z1};
        dist[k] = (v2f){1e10f, 1e10f};
        tab[i0] = make_float4(x0, y0, z0, 0.0f);
        tab[i1] = make_float4(x1, y1, z1, 0.0f);
    }
    __syncthreads();

    float4 c = tab[0];                              // centroid 0 = point 0
    float* ob = new_xyz + (size_t)b * NPOINT * 3;

    for (int it = 0; it < NPOINT; ++it) {
        if (t == 0) {
            ob[it * 3 + 0] = c.x;
            ob[it * 3 + 1] = c.y;
            ob[it * 3 + 2] = c.z;
        }
        const v2f cx2 = (v2f){c.x, c.x};
        const v2f cy2 = (v2f){c.y, c.y};
        const v2f cz2 = (v2f){c.z, c.z};
        float bv = -1.0f;
        int   bi = Nq;
#pragma unroll
        for (int k = 0; k < FPS_PAIRS; ++k) {
            const v2f dx = px[k] - cx2;             // v_pk_add (neg)
            const v2f dy = py[k] - cy2;
            const v2f dz = pz[k] - cz2;
            const v2f sx = dx * dx;                 // v_pk_mul
            const v2f sy = dy * dy;
            const v2f sz = dz * dz;
            const v2f d  = (sx + sy) + sz;          // v_pk_add, L-to-R chain
            const v2f nd = __builtin_elementwise_min(dist[k], d);
            dist[k] = nd;
            if (nd.x > bv) { bv = nd.x; bi = i0c[k]; }   // strict >, asc idx
            if (nd.y > bv) { bv = nd.y; bi = i1c[k]; }
        }
        // pack (value, ~index): u64 max == (max value, tie -> min index)
        unsigned long long k64 =
            ((unsigned long long)__float_as_uint(bv) << 32) |
            (unsigned int)(~bi);
        // wave: row butterfly; 4 row leaders write their row max
        k64 = rowmax16(k64);
        if ((lane & 15) == 0) wbest[it & 1][wid * 4 + (lane >> 4)] = k64;
        __syncthreads();
        // cross-wave: 64 entries, rowmax16 + bcast15/31 collapse -> lane 63
        unsigned long long g = wbest[it & 1][lane];
        g = rowmax16(g);
        DPP_STEP_U64(g, 0x142)                      // row_bcast15: r0->r1, r2->r3
        DPP_STEP_U64(g, 0x143)                      // row_bcast31: r1->r2,r3
        g = readlane_u64(g, 63);
        const int far = (int)(~(unsigned int)(g & 0xffffffffull));
        c = tab[far];                               // uniform addr broadcast
    }
}

// ---------------------------------------------------------------------------
// Kernel 2: ball query, one wave per query (unchanged, verified absmax 0).
// ---------------------------------------------------------------------------
__global__ void __launch_bounds__(256, 4)
ballq_kernel(const float* __restrict__ xyz, const float* __restrict__ new_xyz,
             int* __restrict__ ball_idx)
{
#pragma clang fp contract(off)
    __shared__ int sel[4][NSAMPLE];
    const int w    = threadIdx.x >> 6;
    const int lane = threadIdx.x & 63;
    const int wq   = blockIdx.x * 4 + w;
    const int b    = wq >> 10;

    const float qx = new_xyz[wq * 3 + 0];
    const float qy = new_xyz[wq * 3 + 1];
    const float qz = new_xyz[wq * 3 + 2];
    const float ssrc = qx * qx + qy * qy + qz * qz;   // plain chain
    const float* xb = xyz + (size_t)b * Nq * 3;

    int cnt = 0;
    for (int base = 0; base < Nq; base += 64) {
        const int i = base + lane;
        const float px = xb[i * 3 + 0];
        const float py = xb[i * 3 + 1];
        const float pz = xb[i * 3 + 2];
        const float dot  = __builtin_fmaf(pz, qz, __builtin_fmaf(py, qy, px * qx));
        const float sdst = px * px + py * py + pz * pz;           // plain chain
        const float d    = (-2.0f * dot + ssrc) + sdst;
        const bool  in   = (d <= RAD2);
        const unsigned long long m = __ballot(in);
        if (in) {
            const int slot = cnt + (int)__popcll(m & ((1ull << lane) - 1ull));
            if (slot < NSAMPLE) sel[w][slot] = i;
        }
        cnt += (int)__popcll(m);
        if (cnt >= NSAMPLE) break;
    }
    const int first = sel[w][0];
    if (cnt < NSAMPLE) {
        for (int s = cnt + lane; s < NSAMPLE; s += 64) sel[w][s] = first;
    }
    if (lane < NSAMPLE) ball_idx[(size_t)wq * NSAMPLE + lane] = sel[w][lane];
}

// ---------------------------------------------------------------------------
// Kernel 3: gather + concat (unchanged, verified absmax 0).
// ---------------------------------------------------------------------------
__global__ void __launch_bounds__(256)
fill_kernel(const float* __restrict__ xyz, const float* __restrict__ points,
            const float* __restrict__ new_xyz, const int* __restrict__ ball_idx,
            float* __restrict__ new_points)
{
#pragma clang fp contract(off)
    const int TOT = Bq * NPOINT * NSAMPLE * (3 + DF);
    const int t = blockIdx.x * 256 + threadIdx.x;
    if (t >= TOT) return;
    const int c  = t % (3 + DF);
    const int g  = t / (3 + DF);
    const int bq = g >> 5;
    const int b  = bq >> 10;
    const int idx = ball_idx[g];
    float v;
    if (c < 3) {
        v = xyz[((size_t)b * Nq + idx) * 3 + c] - new_xyz[(size_t)bq * 3 + c];
    } else {
        v = points[((size_t)b * Nq + idx) * DF + (c - 3)];
    }
    new_points[t] = v;
}

// ---------------------------------------------------------------------------
extern "C" void kernel_launch(void* const* d_in, const int* in_sizes, int n_in,
                              void* d_out, int out_size, void* d_ws, size_t ws_size,
                              hipStream_t stream)
{
    (void)in_sizes; (void)n_in; (void)out_size; (void)ws_size;
    const float* xyz    = (const float*)d_in[0];
    const float* points = (const float*)d_in[1];
    float* out        = (float*)d_out;
    float* new_xyz    = out;                               // Bq*NPOINT*3
    float* new_points = out + (size_t)Bq * NPOINT * 3;     // rest
    int*   ball_idx   = (int*)d_ws;                        // Bq*NPOINT*NSAMPLE

    hipFuncSetAttribute(reinterpret_cast<const void*>(fps_kernel),
                        hipFuncAttributeMaxDynamicSharedMemorySize,
                        Nq * (int)sizeof(float4));

    fps_kernel<<<Bq, FPS_T, Nq * sizeof(float4), stream>>>(xyz, new_xyz);
    ballq_kernel<<<(Bq * NPOINT) / 4, 256, 0, stream>>>(xyz, new_xyz, ball_idx);
    const int TOT = Bq * NPOINT * NSAMPLE * (3 + DF);
    fill_kernel<<<(TOT + 255) / 256, 256, 0, stream>>>(xyz, points, new_xyz,
                                                       ball_idx, new_points);
}